// Round 1
// baseline (933.637 us; speedup 1.0000x reference)
//
#include <hip/hip_runtime.h>
#include <hip/hip_bf16.h>

// CTR-GCN fused block. Sizes fixed per reference.
#define N_   128
#define CIN  64
#define COUT 64
#define T_   256
#define V_   25
#define R_   8

// ---------------------------------------------------------------------------
// K1: xm[n,c,v] = (1/T) * sum_t x[n,c,t,v].  One block per (n,c).
// ---------------------------------------------------------------------------
__global__ void k_xm(const float* __restrict__ x, float* __restrict__ xm) {
    int nc = blockIdx.x;                      // n*64 + c
    const float* xp = x + (size_t)nc * (T_ * V_);
    int tid = threadIdx.x;                    // 256
    int v = tid & 31;
    int g = tid >> 5;                         // 0..7
    float s = 0.f;
    if (v < V_) {
        for (int t = g; t < T_; t += 8)
            s += xp[t * V_ + v];
    }
    __shared__ float lds[8][V_];
    if (v < V_) lds[g][v] = s;
    __syncthreads();
    if (tid < V_) {
        float a = 0.f;
#pragma unroll
        for (int i = 0; i < 8; i++) a += lds[i][tid];
        xm[(size_t)nc * V_ + tid] = a * (1.0f / (float)T_);
    }
}

// ---------------------------------------------------------------------------
// K2: per-n attention map.
//   x1[r,v] = sum_c W1[r,c]*xm[n,c,v] + b1[r]   (xm already has /T)
//   x2 likewise
//   y[r,u,v] = tanh(x1[r,u] - x2[r,v])
//   adj[n,o,u,v] = sum_r W4[o,r]*y[r,u,v] + b4[o] + A[u,v]
// One block (256 threads) per n.
// ---------------------------------------------------------------------------
__global__ void k_adj(const float* __restrict__ xm, const float* __restrict__ A,
                      const float* __restrict__ W1, const float* __restrict__ b1,
                      const float* __restrict__ W2, const float* __restrict__ b2,
                      const float* __restrict__ W4, const float* __restrict__ b4,
                      float* __restrict__ adj) {
    int n = blockIdx.x;
    int tid = threadIdx.x;
    __shared__ float xs[CIN * V_];            // xm[n]
    __shared__ float x1s[R_ * V_], x2s[R_ * V_];
    __shared__ float ys[R_ * V_ * V_];        // 5000 floats

    for (int i = tid; i < CIN * V_; i += 256) xs[i] = xm[(size_t)n * CIN * V_ + i];
    __syncthreads();

    if (tid < R_ * V_) {
        int r = tid / V_, v = tid % V_;
        float a1 = b1[r], a2 = b2[r];
#pragma unroll
        for (int c = 0; c < CIN; c++) {
            float xv = xs[c * V_ + v];
            a1 += W1[r * CIN + c] * xv;
            a2 += W2[r * CIN + c] * xv;
        }
        x1s[tid] = a1;
        x2s[tid] = a2;
    }
    __syncthreads();

    for (int i = tid; i < R_ * V_ * V_; i += 256) {
        int r = i / (V_ * V_), uv = i % (V_ * V_);
        int u = uv / V_, v = uv % V_;
        ys[i] = tanhf(x1s[r * V_ + u] - x2s[r * V_ + v]);
    }
    __syncthreads();

    float* adjn = adj + (size_t)n * COUT * V_ * V_;
    for (int i = tid; i < COUT * V_ * V_; i += 256) {
        int o = i / (V_ * V_), uv = i % (V_ * V_);
        float a = b4[o] + A[uv];
#pragma unroll
        for (int r = 0; r < R_; r++) a += W4[o * R_ + r] * ys[r * V_ * V_ + uv];
        adjn[i] = a;
    }
}

// ---------------------------------------------------------------------------
// K3: fused x3 = W3 @ x + b3  and  z[n,o,t,u] = sum_v adj[n,o,u,v]*x3[n,o,t,v]
// One block per (n, t-tile of TT).  LDS: x tile, x3 tile, W3.
// ---------------------------------------------------------------------------
#define TT 4
__global__ void k_z(const float* __restrict__ x, const float* __restrict__ W3,
                    const float* __restrict__ b3, const float* __restrict__ adj,
                    float* __restrict__ z) {
    int blk = blockIdx.x;
    int n  = blk >> 6;          // / (T_/TT) = /64
    int tb = blk & 63;
    int t0 = tb * TT;
    int tid = threadIdx.x;

    __shared__ float xs [CIN * TT * V_];      // [c][t*25+v]
    __shared__ float x3s[COUT * TT * V_];     // [o][t*25+v]
    __shared__ float w3s[COUT * CIN];

    for (int i = tid; i < COUT * CIN; i += 256) w3s[i] = W3[i];

    const float* xp = x + ((size_t)n * CIN * T_ + t0) * V_;
    for (int i = tid; i < CIN * TT * V_; i += 256) {
        int c = i / (TT * V_), tv = i % (TT * V_);
        xs[i] = xp[(size_t)c * T_ * V_ + tv];
    }
    __syncthreads();

    // x3 tile
    for (int i = tid; i < COUT * TT * V_; i += 256) {
        int o = i / (TT * V_), tv = i % (TT * V_);
        float a = b3[o];
        const float* wr = &w3s[o * CIN];
#pragma unroll
        for (int c = 0; c < CIN; c++) a += wr[c] * xs[c * TT * V_ + tv];
        x3s[i] = a;
    }
    __syncthreads();

    // z: each thread owns (o,u) pairs; adj row held in registers.
    const float* adjn = adj + (size_t)n * COUT * V_ * V_;
    float* zp = z + ((size_t)n * COUT * T_ + t0) * V_;
    for (int p = tid; p < COUT * V_; p += 256) {
        int o = p / V_, u = p % V_;
        float areg[V_];
#pragma unroll
        for (int v = 0; v < V_; v++) areg[v] = adjn[o * V_ * V_ + u * V_ + v];
#pragma unroll
        for (int t = 0; t < TT; t++) {
            float a = 0.f;
            const float* xr = &x3s[o * TT * V_ + t * V_];
#pragma unroll
            for (int v = 0; v < V_; v++) a += areg[v] * xr[v];
            zp[(size_t)o * T_ * V_ + t * V_ + u] = a;
        }
    }
}

// ---------------------------------------------------------------------------
extern "C" void kernel_launch(void* const* d_in, const int* in_sizes, int n_in,
                              void* d_out, int out_size, void* d_ws, size_t ws_size,
                              hipStream_t stream) {
    const float* x  = (const float*)d_in[0];
    const float* A  = (const float*)d_in[1];
    const float* W1 = (const float*)d_in[2];
    const float* b1 = (const float*)d_in[3];
    const float* W2 = (const float*)d_in[4];
    const float* b2 = (const float*)d_in[5];
    const float* W3 = (const float*)d_in[6];
    const float* b3 = (const float*)d_in[7];
    const float* W4 = (const float*)d_in[8];
    const float* b4 = (const float*)d_in[9];
    float* z = (float*)d_out;

    // workspace layout: adj (N*COUT*V*V f32) | xm (N*CIN*V f32)
    float* adj = (float*)d_ws;
    float* xm  = adj + (size_t)N_ * COUT * V_ * V_;

    k_xm <<<dim3(N_ * CIN), dim3(256), 0, stream>>>(x, xm);
    k_adj<<<dim3(N_), dim3(256), 0, stream>>>(xm, A, W1, b1, W2, b2, W4, b4, adj);
    k_z  <<<dim3(N_ * (T_ / TT)), dim3(256), 0, stream>>>(x, W3, b3, adj, z);
}